// Round 8
// baseline (328.129 us; speedup 1.0000x reference)
//
#include <hip/hip_runtime.h>
#include <hip/hip_fp16.h>

// ---------------------------------------------------------------------------
// GATLayer reduces to:  z = h @ Wfc.T ;  h_out[v] = mean_{e: dst[e]==v} z[src[e]]
// (entmax over singleton dim == 1; entmax over a constant segment == 1/deg)
//
// Fast path: bucket_count (LDS hist, 64-node buckets) -> tiny scan ->
//   bin_scatter (packed (ld<<17|src)) -> gemm (z fp16) -> bucket_gather
//   (256-thr block per bucket: LDS counting sort + half-wave half2 gather:
//    lanes 0-31 even edges, 32-63 odd edges, 2 z-rows per load instruction).
// ---------------------------------------------------------------------------

#define WS_ALIGN(x) (((x) + (size_t)255) & ~(size_t)255)
#define BBITS 6
#define BNODES 64             // nodes per bucket
#define CAP 4096              // edges sorted per LDS chunk
#define MAXBUCK 2048

__device__ inline unsigned pack_h2(float a, float b) {
    __half2 h = __floats2half2_rn(a, b);
    return *reinterpret_cast<unsigned*>(&h);
}

// ---- per-bucket edge counts via LDS histogram (few atomics per block) ----
__global__ __launch_bounds__(256) void bucket_count(const int* __restrict__ dst,
                                                    int* __restrict__ bcnt,
                                                    int E, int nbuck) {
    __shared__ int h[MAXBUCK];
    for (int i = threadIdx.x; i < nbuck; i += 256) h[i] = 0;
    __syncthreads();
    int base = blockIdx.x * 16384;
    for (int k = 0; k < 64; k++) {
        int e = base + threadIdx.x + k * 256;
        if (e < E) atomicAdd(&h[dst[e] >> BBITS], 1);
    }
    __syncthreads();
    for (int i = threadIdx.x; i < nbuck; i += 256)
        if (h[i]) atomicAdd(&bcnt[i], h[i]);
}

// ---- exclusive scan of bucket counts (1 block, 1024 thr, nbuck <= 2048) ----
__global__ __launch_bounds__(1024) void scan_buckets(const int* __restrict__ bcnt,
                                                     int* __restrict__ bases,
                                                     int* __restrict__ cur,
                                                     int E, int nbuck) {
    __shared__ int sp[1024];
    int t = threadIdx.x;
    int a = (2 * t < nbuck) ? bcnt[2 * t] : 0;
    int b = (2 * t + 1 < nbuck) ? bcnt[2 * t + 1] : 0;
    sp[t] = a + b;
    __syncthreads();
    for (int off = 1; off < 1024; off <<= 1) {
        int x = (t >= off) ? sp[t - off] : 0;
        __syncthreads();
        sp[t] += x;
        __syncthreads();
    }
    int ex = sp[t] - (a + b);     // exclusive base for element 2t
    if (2 * t < nbuck)     { bases[2 * t] = ex;         cur[2 * t] = ex; }
    if (2 * t + 1 < nbuck) { bases[2 * t + 1] = ex + a; cur[2 * t + 1] = ex + a; }
    if (t == 0) bases[nbuck] = E;
}

// ---- bin edges into bucket-contiguous runs, packed (localdst<<17 | src) ----
__global__ __launch_bounds__(256) void bin_scatter(const int* __restrict__ src,
                                                   const int* __restrict__ dst,
                                                   int* __restrict__ cur,
                                                   unsigned* __restrict__ binned,
                                                   int E, int nbuck) {
    __shared__ int hist[MAXBUCK], gbase[MAXBUCK], cnt2[MAXBUCK];
    int base = blockIdx.x * 16384;
    for (int i = threadIdx.x; i < nbuck; i += 256) { hist[i] = 0; cnt2[i] = 0; }
    __syncthreads();
    for (int k = 0; k < 64; k++) {
        int e = base + threadIdx.x + k * 256;
        if (e < E) atomicAdd(&hist[dst[e] >> BBITS], 1);
    }
    __syncthreads();
    for (int i = threadIdx.x; i < nbuck; i += 256)
        if (hist[i]) gbase[i] = atomicAdd(&cur[i], hist[i]);
    __syncthreads();
    for (int k = 0; k < 64; k++) {
        int e = base + threadIdx.x + k * 256;
        if (e < E) {
            int d = dst[e];
            int b = d >> BBITS;
            int lo = atomicAdd(&cnt2[b], 1);
            binned[gbase[b] + lo] = ((unsigned)(d & (BNODES - 1)) << 17) |
                                    (unsigned)src[e];
        }
    }
}

// ---- z = h @ W.T, fp16 out. W (32 KB) in LDS, broadcast reads. ----
__global__ __launch_bounds__(256) void gemm_z(const float* __restrict__ h,
                                              const float* __restrict__ W,
                                              __half* __restrict__ z, int N) {
    __shared__ float Wl[64 * 128];
    for (int j = threadIdx.x; j < 2048; j += 256) {
        reinterpret_cast<float4*>(Wl)[j] = reinterpret_cast<const float4*>(W)[j];
    }
    __syncthreads();
    int row = blockIdx.x * 256 + threadIdx.x;
    if (row >= N) return;
    float acc[64];
#pragma unroll
    for (int c = 0; c < 64; c++) acc[c] = 0.f;
    const float4* hr = reinterpret_cast<const float4*>(&h[(size_t)row * 128]);
    for (int kv = 0; kv < 32; kv++) {
        float4 hv = hr[kv];
#pragma unroll
        for (int c = 0; c < 64; c++) {
            float4 wv = *reinterpret_cast<const float4*>(&Wl[c * 128 + kv * 4]);
            acc[c] += hv.x * wv.x + hv.y * wv.y + hv.z * wv.z + hv.w * wv.w;
        }
    }
    uint4* zr = reinterpret_cast<uint4*>(&z[(size_t)row * 64]);
#pragma unroll
    for (int c = 0; c < 8; c++) {
        uint4 pk;
        pk.x = pack_h2(acc[8 * c + 0], acc[8 * c + 1]);
        pk.y = pack_h2(acc[8 * c + 2], acc[8 * c + 3]);
        pk.z = pack_h2(acc[8 * c + 4], acc[8 * c + 5]);
        pk.w = pack_h2(acc[8 * c + 6], acc[8 * c + 7]);
        zr[c] = pk;
    }
}

// ---- one 256-thr block per 64-node bucket: LDS counting sort + half-wave
// half2 gather. 4 waves; wave w owns nodes [w*16, w*16+16).
// Within a wave: lanes 0-31 = even edges, lanes 32-63 = odd edges; each lane
// loads __half2 (cols 2c,2c+1) -> one instruction fetches TWO z-rows.
__global__ __launch_bounds__(256) void bucket_gather(
        const unsigned* __restrict__ binned,
        const int* __restrict__ bases,
        const __half* __restrict__ z,
        float* __restrict__ out, int N) {
    __shared__ unsigned sed[CAP];       // srcs sorted by local dst (16 KB)
    __shared__ int hist[BNODES];
    __shared__ int ioff[BNODES];        // inclusive offsets (chunk)
    __shared__ int eoff[BNODES];        // exclusive offsets (chunk)
    __shared__ int curs[BNODES];
    __shared__ int degl[BNODES];        // total degree across chunks

    int b = blockIdx.x;
    int s0 = bases[b], s1 = bases[b + 1];
    int tid = threadIdx.x;
    int wid = tid >> 6, lane = tid & 63;
    int half = lane >> 5;               // 0: even edges, 1: odd edges
    int c = lane & 31;                  // column-pair index (cols 2c, 2c+1)

    if (tid < BNODES) degl[tid] = 0;

    float2 acc[16];
#pragma unroll
    for (int s = 0; s < 16; s++) acc[s] = make_float2(0.f, 0.f);

    const __half2* z2 = reinterpret_cast<const __half2*>(z);

    for (int c0 = s0; c0 < s1; c0 += CAP) {
        int cnt = s1 - c0;
        if (cnt > CAP) cnt = CAP;
        if (tid < BNODES) hist[tid] = 0;
        __syncthreads();
        for (int i = tid; i < cnt; i += 256) {
            unsigned p = binned[c0 + i];
            atomicAdd(&hist[(p >> 17) & (BNODES - 1)], 1);
        }
        __syncthreads();
        if (tid < 64) {                 // single-wave shfl scan
            int v = hist[tid];
            int inc = v;
#pragma unroll
            for (int off = 1; off < 64; off <<= 1) {
                int x = __shfl_up(inc, off);
                if (tid >= off) inc += x;
            }
            ioff[tid] = inc;
            eoff[tid] = inc - v;
            curs[tid] = inc - v;
            degl[tid] += v;
        }
        __syncthreads();
        for (int i = tid; i < cnt; i += 256) {
            unsigned p = binned[c0 + i];
            int ld = (p >> 17) & (BNODES - 1);
            int pos = atomicAdd(&curs[ld], 1);
            sed[pos] = p & 0x1FFFFu;
        }
        __syncthreads();
#pragma unroll
        for (int s = 0; s < 16; s++) {
            int r = wid * 16 + s;
            int e0 = eoff[r], e1 = ioff[r];
            float2 f0 = make_float2(0.f, 0.f), f1 = f0, f2 = f0, f3 = f0;
            int idx = e0 + half;        // this half's first edge (stride 2)
            for (; idx + 6 < e1; idx += 8) {   // 4 pairs in flight = 8 rows/wave
                int q0 = sed[idx];
                int q1 = sed[idx + 2];
                int q2 = sed[idx + 4];
                int q3 = sed[idx + 6];
                float2 v0 = __half22float2(z2[(size_t)q0 * 32 + c]);
                float2 v1 = __half22float2(z2[(size_t)q1 * 32 + c]);
                float2 v2 = __half22float2(z2[(size_t)q2 * 32 + c]);
                float2 v3 = __half22float2(z2[(size_t)q3 * 32 + c]);
                f0.x += v0.x; f0.y += v0.y;
                f1.x += v1.x; f1.y += v1.y;
                f2.x += v2.x; f2.y += v2.y;
                f3.x += v3.x; f3.y += v3.y;
            }
            for (; idx < e1; idx += 2) {
                float2 v = __half22float2(z2[(size_t)sed[idx] * 32 + c]);
                f0.x += v.x; f0.y += v.y;
            }
            acc[s].x += (f0.x + f1.x) + (f2.x + f3.x);
            acc[s].y += (f0.y + f1.y) + (f2.y + f3.y);
        }
        __syncthreads();   // protect sed/ioff/eoff before next chunk
    }
    // combine half-wave partials and write out; halves write alternating nodes
    int node0 = b << BBITS;
#pragma unroll
    for (int s = 0; s < 16; s++) {
        float2 tot;
        tot.x = acc[s].x + __shfl_xor(acc[s].x, 32);
        tot.y = acc[s].y + __shfl_xor(acc[s].y, 32);
        int node = node0 + wid * 16 + s;
        if ((s & 1) == half && node < N) {
            int d = degl[wid * 16 + s];
            float sc = (d > 0) ? 1.0f / (float)d : 0.f;
            tot.x *= sc; tot.y *= sc;
            reinterpret_cast<float2*>(out + (size_t)node * 64)[c] = tot;
        }
    }
}

// ---- fallback path (small ws / odd shapes): atomic scatter-add ----
__global__ __launch_bounds__(256) void count_deg(const int* __restrict__ dst,
                                                 int* __restrict__ cnt, int E) {
    int e = blockIdx.x * 256 + threadIdx.x;
    if (e < E) atomicAdd(&cnt[dst[e]], 1);
}

__global__ __launch_bounds__(256) void edge_add(const __half* __restrict__ z,
                                                const int* __restrict__ src,
                                                const int* __restrict__ dst,
                                                float* __restrict__ out, int E) {
    int e = blockIdx.x * 4 + (threadIdx.x >> 6);
    int lane = threadIdx.x & 63;
    if (e >= E) return;
    int s = src[e];
    int d = dst[e];
    float v = __half2float(z[(size_t)s * 64 + lane]);
    atomicAdd(&out[(size_t)d * 64 + lane], v);
}

__global__ __launch_bounds__(256) void scale_out(float* __restrict__ out,
                                                 const int* __restrict__ deg, int N) {
    int v = blockIdx.x * 4 + (threadIdx.x >> 6);
    int lane = threadIdx.x & 63;
    if (v >= N) return;
    int d = deg[v];
    if (d > 0) out[(size_t)v * 64 + lane] *= (1.0f / (float)d);
}

extern "C" void kernel_launch(void* const* d_in, const int* in_sizes, int n_in,
                              void* d_out, int out_size, void* d_ws, size_t ws_size,
                              hipStream_t stream) {
    const float* h   = (const float*)d_in[0];
    const int*   src = (const int*)d_in[2];
    const int*   dst = (const int*)d_in[3];
    const float* Wfc = (const float*)d_in[4];
    float*       out = (float*)d_out;

    int N = in_sizes[0] / 128;
    int E = in_sizes[2];
    (void)n_in; (void)out_size;

    int nbuck = (N + BNODES - 1) >> BBITS;

    size_t sz_z    = WS_ALIGN((size_t)N * 64 * sizeof(__half));
    size_t sz_bin  = WS_ALIGN((size_t)E * sizeof(unsigned));
    size_t sz_bkt  = WS_ALIGN((size_t)(3 * MAXBUCK + 2) * sizeof(int));
    size_t need_fast = sz_z + sz_bin + sz_bkt;

    char*     ws     = (char*)d_ws;
    __half*   z      = (__half*)ws;
    unsigned* binned = (unsigned*)(ws + sz_z);
    int*      bcnt   = (int*)(ws + sz_z + sz_bin);
    int*      bases  = bcnt + MAXBUCK;            // nbuck+1 entries
    int*      cur    = bases + MAXBUCK + 2;

    int nwgE = (E + 16383) / 16384;

    bool can_fast = (N <= (1 << 17)) && (nbuck <= MAXBUCK) &&
                    (ws_size >= need_fast);

    if (can_fast) {
        hipMemsetAsync(bcnt, 0, (size_t)nbuck * sizeof(int), stream);
        bucket_count<<<nwgE, 256, 0, stream>>>(dst, bcnt, E, nbuck);
        scan_buckets<<<1, 1024, 0, stream>>>(bcnt, bases, cur, E, nbuck);
        bin_scatter<<<nwgE, 256, 0, stream>>>(src, dst, cur, binned, E, nbuck);
        gemm_z<<<(N + 255) / 256, 256, 0, stream>>>(h, Wfc, z, N);
        bucket_gather<<<nbuck, 256, 0, stream>>>(binned, bases, z, out, N);
    } else if (ws_size >= sz_z + WS_ALIGN((size_t)N * sizeof(int))) {
        // atomic scatter-add fallback
        int* deg = (int*)(ws + sz_z);
        hipMemsetAsync(deg, 0, (size_t)N * sizeof(int), stream);
        hipMemsetAsync(out, 0, (size_t)N * 64 * sizeof(float), stream);
        count_deg<<<(E + 255) / 256, 256, 0, stream>>>(dst, deg, E);
        gemm_z<<<(N + 255) / 256, 256, 0, stream>>>(h, Wfc, z, N);
        edge_add<<<(E + 3) / 4, 256, 0, stream>>>(z, src, dst, out, E);
        scale_out<<<(N + 3) / 4, 256, 0, stream>>>(out, deg, N);
    }
}